// Round 10
// baseline (351.641 us; speedup 1.0000x reference)
//
#include <hip/hip_runtime.h>
#include <math.h>

#define NH 4
#define DIM 512
#define VDIM 512
#define QDIM 1024
#define KS 100
#define KN 100
#define TEMPERATURE 0.5f
#define BS 8
#define TS 2048
#define NHD (NH * DIM)          // 2048

// workspace layout (floats)
#define WS_QUERY  0                       // 16384
#define WS_QTAB   16384                   // 202*512 = 103424
#define WS_ENERGY 119808                  // 65536
#define WS_CTX    185344                  // 16384
#define WS_P      201728                  // 202*100 = 20200
#define WS_F32_END 221928                 // *4 bytes
// bf16 region: enc_bf [8388608 el], wk_bf [1048576], wv_bf [1048576]

typedef __bf16 bf16x8 __attribute__((ext_vector_type(8)));
typedef __bf16 bf16x4 __attribute__((ext_vector_type(4)));
typedef float  f32x4  __attribute__((ext_vector_type(4)));

#define AS1(p) ((const __attribute__((address_space(1))) void*)(p))
#define AS3(p) ((__attribute__((address_space(3))) void*)(p))

__device__ __forceinline__ float fast_tanh(float x) {
    float xc = fminf(fmaxf(x, -9.0f), 9.0f);
    float e = __expf(2.0f * xc);
    return __fdividef(e - 1.0f, e + 1.0f);
}

// ---------------------------------------------------------------------------
// merged: fp32->bf16 cvt (3 tensors) + query GEMV
// ---------------------------------------------------------------------------
#define NE4 (BS * TS * VDIM / 4)      // 2097152
#define NW4 (NHD * VDIM / 4)          // 262144
#define NCVT ((NE4 + 2 * NW4) / 256)  // 10240 cvt blocks
#define NQRY (BS * NHD / 4)           // 4096 query blocks
__global__ void k_precvt(const float* __restrict__ enc, const float* __restrict__ Wk,
                         const float* __restrict__ Wv, __bf16* __restrict__ enc_bf,
                         __bf16* __restrict__ wk_bf, __bf16* __restrict__ wv_bf,
                         const float* __restrict__ dec, const float* __restrict__ Wq,
                         const float* __restrict__ bq, float* __restrict__ query) {
    if (blockIdx.x < NCVT) {
        int i = blockIdx.x * blockDim.x + threadIdx.x;
        const float* src; __bf16* dst; int k;
        if (i < NE4)            { src = enc; dst = enc_bf; k = i; }
        else if (i < NE4 + NW4) { src = Wk;  dst = wk_bf;  k = i - NE4; }
        else                    { src = Wv;  dst = wv_bf;  k = i - NE4 - NW4; }
        float4 v = ((const float4*)src)[k];
        bf16x4 o;
        o[0] = (__bf16)v.x; o[1] = (__bf16)v.y; o[2] = (__bf16)v.z; o[3] = (__bf16)v.w;
        ((bf16x4*)dst)[k] = o;
    } else {
        int q = blockIdx.x - NCVT;                       // 0..4095
        int w = q * 4 + (threadIdx.x >> 6);              // wave id = output id
        int lane = threadIdx.x & 63;
        int b = w >> 11;
        int o = w & 2047;
        const float* dr = dec + b * QDIM;
        const float* wr = Wq + o * QDIM;
        float s = 0.f;
        #pragma unroll
        for (int i = 0; i < QDIM / 64; ++i)
            s = fmaf(dr[lane + 64 * i], wr[lane + 64 * i], s);
        #pragma unroll
        for (int off = 32; off > 0; off >>= 1) s += __shfl_down(s, off);
        if (lane == 0) query[b * NHD + o] = tanhf(s + bq[o]);
    }
}

// ---------------------------------------------------------------------------
// conv prefix, fast: phase A stages head-summed weights to LDS (coalesced),
// phase B does the 201-step scan per k out of LDS (L1-speed).
// P[j][k] = sum_{dt<j} sum_h convw[k,h,dt]
// ---------------------------------------------------------------------------
__global__ void k_prefix(const float* __restrict__ convw, float* __restrict__ P) {
    __shared__ float cs[KN * (2 * KS + 1)];    // 100*201 floats = 80.4 KB
    int tid = threadIdx.x;                     // 1024
    for (int i = tid; i < KN * (2 * KS + 1); i += 1024) {
        int k = i / (2 * KS + 1);
        int dt = i - k * (2 * KS + 1);
        const float* wr = convw + k * (NH * (2 * KS + 1)) + dt;
        cs[i] = wr[0] + wr[201] + wr[402] + wr[603];
    }
    __syncthreads();
    if (tid < KN) {
        float acc = 0.f;
        P[tid] = 0.f;
        const float* c = cs + tid * (2 * KS + 1);
        for (int dt = 0; dt < 2 * KS + 1; ++dt) {
            acc += c[dt];
            P[(dt + 1) * KN + tid] = acc;
        }
    }
}

// ---------------------------------------------------------------------------
// Qtab[j,d] = sum_k projw[d,k] * P[j,k]
// ---------------------------------------------------------------------------
__global__ void k_qtab(const float* __restrict__ P, const float* __restrict__ projw,
                       float* __restrict__ Qtab) {
    int j = blockIdx.x;       // 0..201
    __shared__ float Pc[KN];
    int tid = threadIdx.x;    // 512
    if (tid < KN) Pc[tid] = P[j * KN + tid];
    __syncthreads();
    const float* pr = projw + tid * KN;
    float s = 0.f;
    #pragma unroll 4
    for (int k = 0; k < KN; ++k) s = fmaf(pr[k], Pc[k], s);
    Qtab[j * DIM + tid] = s;
}

// ===========================================================================
// GEMM core v4: 128x256 block tile, BK=32, 1024 threads = 16 waves in a
// 2(t) x 8(n) wave grid, wave tile 64x32 (acc 32 regs -> no spills, VGPR~72).
// Halves the L3-borne A staging vs 128x128 (8 n-blocks instead of 16), and
// with XCD = bid&7 each XCD owns exactly ONE 256-row B slice (256 KB,
// L2-resident). Double-buffered LDS (48 KB), one barrier/iter,
// loop-invariant addresses (BK=32 XOR swizzle).
// Grid: bid = ((b*16 + tb)<<3) | nb;  t0 = tb*128, n0 = nb*256.
// ===========================================================================
#define GEMM1(Bptr)                                                               \
    const int bid = blockIdx.x;                                                    \
    const int b   = bid >> 7;                                                      \
    const int t0  = ((bid >> 3) & 15) << 7;                                        \
    const int n0  = (bid & 7) << 8;                                                \
    const int len = enc_len[b];                                                    \
    if (t0 >= len) return;                                                         \
    const int tid = threadIdx.x;                                                   \
    const int w = tid >> 6, lane = tid & 63;                                       \
    const int wy = w >> 3, wx = w & 7;                                             \
    const int col = lane & 15, quad = lane >> 4;                                   \
    __shared__ __bf16 Ash[2 * 4096];                                               \
    __shared__ __bf16 Bsh[2 * 8192];                                               \
    f32x4 acc[4][2];                                                               \
    _Pragma("unroll")                                                              \
    for (int i = 0; i < 4; ++i)                                                    \
        _Pragma("unroll")                                                          \
        for (int j = 0; j < 2; ++j) acc[i][j] = (f32x4)0.f;                        \
    const __bf16* Abase = enc_bf + ((size_t)b * TS + t0) * VDIM;                   \
    const int mB_ = tid >> 2;                                                      \
    const int cB_ = (tid & 3) ^ (mB_ & 3) ^ ((mB_ >> 2) & 3);                      \
    const __bf16* gpB = (Bptr) + ((size_t)n0 + mB_) * VDIM + cB_ * 8;              \
    const int mA_ = (tid & 511) >> 2;                                              \
    const int cA_ = (tid & 3) ^ (mA_ & 3) ^ ((mA_ >> 2) & 3);                      \
    const __bf16* gpA = Abase + (size_t)mA_ * VDIM + cA_ * 8;                      \
    const int cfr = quad ^ (col & 3) ^ ((col >> 2) & 3);                           \
    const char* pA = (const char*)Ash + (((wy * 64 + col) * 4 + cfr) << 4);        \
    const char* pB = (const char*)Bsh + (((wx * 32 + col) * 4 + cfr) << 4);        \
    if (tid < 512)                                                                 \
        __builtin_amdgcn_global_load_lds(AS1(gpA), AS3(Ash + tid * 8), 16, 0, 0);  \
    __builtin_amdgcn_global_load_lds(AS1(gpB), AS3(Bsh + tid * 8), 16, 0, 0);      \
    gpA += 32; gpB += 32;                                                          \
    for (int kk = 0; kk < 16; ++kk) {                                              \
        __syncthreads();                                                           \
        if (kk < 15) {                                                             \
            const int par = (kk + 1) & 1;                                          \
            if (tid < 512)                                                         \
                __builtin_amdgcn_global_load_lds(AS1(gpA),                         \
                    AS3(Ash + par * 4096 + tid * 8), 16, 0, 0);                    \
            __builtin_amdgcn_global_load_lds(AS1(gpB),                             \
                AS3(Bsh + par * 8192 + tid * 8), 16, 0, 0);                        \
            gpA += 32; gpB += 32;                                                  \
        }                                                                          \
        const int boA = (kk & 1) * 8192;                                           \
        const int boB = (kk & 1) * 16384;                                          \
        bf16x8 af[4], bfr[2];                                                      \
        _Pragma("unroll")                                                          \
        for (int i = 0; i < 4; ++i) af[i] = *(const bf16x8*)(pA + boA + i * 1024); \
        _Pragma("unroll")                                                          \
        for (int j = 0; j < 2; ++j) bfr[j] = *(const bf16x8*)(pB + boB + j * 1024);\
        _Pragma("unroll")                                                          \
        for (int i = 0; i < 4; ++i)                                                \
            _Pragma("unroll")                                                      \
            for (int j = 0; j < 2; ++j)                                            \
                acc[i][j] = __builtin_amdgcn_mfma_f32_16x16x32_bf16(               \
                    af[i], bfr[j], acc[i][j], 0, 0, 0);                            \
    }                                                                              \
    __syncthreads();
// acc[i][j][r] = C[t0+wy*64+i*16+quad*4+r][n0+wx*32+j*16+col]

// ---------------------------------------------------------------------------
// Energy pass: C = enc @ Wk^T, epilogue:
//   energy[b,h,t] += sum_n tanh(tanh(C+bk)+query+loc) * gen_w[d]
// ---------------------------------------------------------------------------
__global__ __launch_bounds__(1024, 4) void k_energy(
    const __bf16* __restrict__ enc_bf, const __bf16* __restrict__ wk_bf,
    const float* __restrict__ bk, const float* __restrict__ gen_w,
    const int* __restrict__ enc_len, const float* __restrict__ query,
    const float* __restrict__ Qtab, float* __restrict__ energy) {
    GEMM1(wk_bf)

    const int h = n0 >> 9;
    const float inv_len = 1.0f / (float)len;
    float qv[2], gw[2], bkv[2], lI[2];
    int dj[2];
    #pragma unroll
    for (int j = 0; j < 2; ++j) {
        int n = n0 + wx * 32 + j * 16 + col;
        dj[j] = n & (DIM - 1);
        qv[j] = query[b * NHD + n];
        gw[j] = gen_w[dj[j]];
        bkv[j] = bk[n];
        lI[j] = fast_tanh((Qtab[(2 * KS + 1) * DIM + dj[j]] - Qtab[dj[j]]) * inv_len);
    }
    float* red = (float*)Ash;   // [128][8]
    #pragma unroll
    for (int i = 0; i < 4; ++i) {
        #pragma unroll
        for (int r = 0; r < 4; ++r) {
            int tl = wy * 64 + i * 16 + quad * 4 + r;
            int t = t0 + tl;
            float l[2];
            if (t >= KS && t < len - KS) {           // interior: loc const in t
                #pragma unroll
                for (int j = 0; j < 2; ++j) l[j] = lI[j];
            } else {
                int lo = KS - t; if (lo < 0) lo = 0;
                int hi = KS - t + len - 1; if (hi > 2 * KS) hi = 2 * KS;
                bool has = (hi >= lo);
                #pragma unroll
                for (int j = 0; j < 2; ++j) {
                    float cv = has
                        ? (Qtab[(hi + 1) * DIM + dj[j]] - Qtab[lo * DIM + dj[j]]) * inv_len
                        : 0.f;
                    l[j] = fast_tanh(cv);
                }
            }
            float s = 0.f;
            #pragma unroll
            for (int j = 0; j < 2; ++j) {
                float key = fast_tanh(acc[i][j][r] + bkv[j]);
                float e = fast_tanh(key + qv[j] + l[j]);
                s = fmaf(e, gw[j], s);
            }
            s += __shfl_xor(s, 1); s += __shfl_xor(s, 2);
            s += __shfl_xor(s, 4); s += __shfl_xor(s, 8);
            if (col == 0) red[tl * 8 + wx] = s;
        }
    }
    __syncthreads();
    if (tid < 128) {
        float s = 0.f;
        #pragma unroll
        for (int x = 0; x < 8; ++x) s += red[tid * 8 + x];
        atomicAdd(&energy[(size_t)(b * NH + h) * TS + t0 + tid], s);
    }
}

// ---------------------------------------------------------------------------
// ctx pass: C = enc @ Wv^T, epilogue: ctx[b,n] += sum_t attn * tanh(C + bv)
// ---------------------------------------------------------------------------
__global__ __launch_bounds__(1024, 4) void k_ctxg(
    const __bf16* __restrict__ enc_bf, const __bf16* __restrict__ wv_bf,
    const float* __restrict__ bv, const float* __restrict__ attn,
    const int* __restrict__ enc_len, float* __restrict__ ctx) {
    GEMM1(wv_bf)

    const int h = n0 >> 9;
    float att[4][4];
    #pragma unroll
    for (int i = 0; i < 4; ++i)
        #pragma unroll
        for (int r = 0; r < 4; ++r)
            att[i][r] = attn[(size_t)(b * NH + h) * TS + t0 + wy * 64 + i * 16 + quad * 4 + r];
    float* red = (float*)Ash;   // [256][2]
    #pragma unroll
    for (int j = 0; j < 2; ++j) {
        int nl = wx * 32 + j * 16 + col;
        float bvn = bv[n0 + nl];
        float s = 0.f;
        #pragma unroll
        for (int i = 0; i < 4; ++i)
            #pragma unroll
            for (int r = 0; r < 4; ++r)
                s = fmaf(att[i][r], fast_tanh(acc[i][j][r] + bvn), s);
        s += __shfl_xor(s, 16); s += __shfl_xor(s, 32);
        if (quad == 0) red[nl * 2 + wy] = s;
    }
    __syncthreads();
    if (tid < 256) {
        float s = red[tid * 2] + red[tid * 2 + 1];
        atomicAdd(&ctx[(size_t)b * NHD + n0 + tid], s);
    }
}

// ---------------------------------------------------------------------------
// softmax over t (masked), shuffle-based, writes attn to d_out
// ---------------------------------------------------------------------------
__global__ void k_softmax(const float* __restrict__ energy, const int* __restrict__ enc_len,
                          const float* __restrict__ gen_b, float* __restrict__ attn) {
    int bh = blockIdx.x;          // 32
    int b = bh >> 2;
    int len = enc_len[b];
    int tid = threadIdx.x;        // 512
    int w = tid >> 6, lane = tid & 63;
    const float gb = gen_b[0];
    float ev[4];
    float mx = -INFINITY;
    #pragma unroll
    for (int i = 0; i < 4; ++i) {
        int t = i * 512 + tid;
        float e = (t < len) ? (energy[(size_t)bh * TS + t] + gb) * (1.0f / TEMPERATURE)
                            : -INFINITY;
        ev[i] = e;
        mx = fmaxf(mx, e);
    }
    __shared__ float sred[8], ssum[8];
    #pragma unroll
    for (int off = 32; off > 0; off >>= 1) mx = fmaxf(mx, __shfl_xor(mx, off));
    if (lane == 0) sred[w] = mx;
    __syncthreads();
    #pragma unroll
    for (int k = 0; k < 8; ++k) mx = fmaxf(mx, sred[k]);
    float ls = 0.f;
    #pragma unroll
    for (int i = 0; i < 4; ++i) {
        float ex = __expf(ev[i] - mx);
        ev[i] = ex;
        ls += ex;
    }
    #pragma unroll
    for (int off = 32; off > 0; off >>= 1) ls += __shfl_xor(ls, off);
    if (lane == 0) ssum[w] = ls;
    __syncthreads();
    float tot = 0.f;
    #pragma unroll
    for (int k = 0; k < 8; ++k) tot += ssum[k];
    float inv = 1.0f / tot;
    #pragma unroll
    for (int i = 0; i < 4; ++i)
        attn[(size_t)bh * TS + i * 512 + tid] = ev[i] * inv;
}

// ---------------------------------------------------------------------------
// context[b,o] = ctx[b,:] . merge_w[o,:] + merge_b[o];  one wave per output
// ---------------------------------------------------------------------------
__global__ void k_merge(const float* __restrict__ ctx, const float* __restrict__ mw,
                        const float* __restrict__ mb, float* __restrict__ out) {
    int w = (blockIdx.x * blockDim.x + threadIdx.x) >> 6;
    int lane = threadIdx.x & 63;
    int b = w >> 9;
    int o = w & 511;
    const float* c = ctx + (size_t)b * NHD;
    const float* wr = mw + (size_t)o * NHD;
    float s = 0.f;
    #pragma unroll
    for (int i = 0; i < NHD / 64; ++i) s = fmaf(c[lane + 64 * i], wr[lane + 64 * i], s);
    #pragma unroll
    for (int off = 32; off > 0; off >>= 1) s += __shfl_down(s, off);
    if (lane == 0) out[b * VDIM + o] = s + mb[o];
}

extern "C" void kernel_launch(void* const* d_in, const int* in_sizes, int n_in,
                              void* d_out, int out_size, void* d_ws, size_t ws_size,
                              hipStream_t stream) {
    const float* dec     = (const float*)d_in[0];
    const float* enc     = (const float*)d_in[1];
    const int*   enc_len = (const int*)d_in[2];
    const float* Wq      = (const float*)d_in[3];
    const float* bq      = (const float*)d_in[4];
    const float* Wk      = (const float*)d_in[5];
    const float* bk      = (const float*)d_in[6];
    const float* Wv      = (const float*)d_in[7];
    const float* bv      = (const float*)d_in[8];
    const float* convw   = (const float*)d_in[9];
    const float* projw   = (const float*)d_in[10];
    const float* gen_w   = (const float*)d_in[11];
    const float* gen_b   = (const float*)d_in[12];
    const float* merge_w = (const float*)d_in[13];
    const float* merge_b = (const float*)d_in[14];

    float* out   = (float*)d_out;               // attn [65536] ++ context [4096]
    float* ws    = (float*)d_ws;
    float* query = ws + WS_QUERY;
    float* Qtab  = ws + WS_QTAB;
    float* energy= ws + WS_ENERGY;
    float* ctx   = ws + WS_CTX;
    float* Pws   = ws + WS_P;
    __bf16* enc_bf = (__bf16*)((char*)d_ws + (size_t)WS_F32_END * 4);
    __bf16* wk_bf  = enc_bf + (size_t)BS * TS * VDIM;
    __bf16* wv_bf  = wk_bf + (size_t)NHD * VDIM;

    // zero atomic accumulators (energy + ctx contiguous)
    hipMemsetAsync(energy, 0, (65536 + 16384) * sizeof(float), stream);

    k_prefix<<<dim3(1), dim3(1024), 0, stream>>>(convw, Pws);
    k_precvt<<<dim3(NCVT + NQRY), dim3(256), 0, stream>>>(
        enc, Wk, Wv, enc_bf, wk_bf, wv_bf, dec, Wq, bq, query);
    k_qtab<<<dim3(2 * KS + 2), dim3(512), 0, stream>>>(Pws, projw, Qtab);
    k_energy<<<dim3(1024), dim3(1024), 0, stream>>>(
        enc_bf, wk_bf, bk, gen_w, enc_len, query, Qtab, energy);
    k_softmax<<<dim3(BS * NH), dim3(512), 0, stream>>>(energy, enc_len, gen_b, out);
    k_ctxg<<<dim3(1024), dim3(1024), 0, stream>>>(
        enc_bf, wv_bf, bv, out, enc_len, ctx);
    k_merge<<<dim3(BS * VDIM / 4), dim3(256), 0, stream>>>(ctx, merge_w, merge_b, out + 65536);
}

// Round 11
// 310.846 us; speedup vs baseline: 1.1312x; 1.1312x over previous
//
#include <hip/hip_runtime.h>
#include <math.h>

#define NH 4
#define DIM 512
#define VDIM 512
#define QDIM 1024
#define KS 100
#define KN 100
#define TEMPERATURE 0.5f
#define BS 8
#define TS 2048
#define NHD (NH * DIM)          // 2048

// workspace layout (floats)
#define WS_QUERY  0                       // 16384
#define WS_QTAB   16384                   // 202*512 = 103424
#define WS_ENERGY 119808                  // 65536
#define WS_CTX    185344                  // 16384  (contiguous after energy)
#define WS_P      201728                  // 202*100 = 20200
#define WS_F32_END 221928                 // *4 bytes
// bf16 region: enc_bf [8388608 el], wk_bf [1048576], wv_bf [1048576]

typedef __bf16 bf16x8 __attribute__((ext_vector_type(8)));
typedef __bf16 bf16x4 __attribute__((ext_vector_type(4)));
typedef float  f32x4  __attribute__((ext_vector_type(4)));

#define AS1(p) ((const __attribute__((address_space(1))) void*)(p))
#define AS3(p) ((__attribute__((address_space(3))) void*)(p))

__device__ __forceinline__ float fast_tanh(float x) {
    float xc = fminf(fmaxf(x, -9.0f), 9.0f);
    float e = __expf(2.0f * xc);
    return __fdividef(e - 1.0f, e + 1.0f);
}

// ---------------------------------------------------------------------------
// k_pre: one dispatch doing 4 independent jobs:
//   [0, NCVT)           fp32->bf16 cvt of enc/Wk/Wv
//   [NCVT, +NQ2)        query GEMV: one WAVE per output o, loops all 8
//                       batches -> Wq read once (8 MB not 64 MB)
//   [NCVT+NQ2]          conv prefix (LDS-staged)
//   rest                zero energy+ctx accumulators (replaces hipMemset)
// ---------------------------------------------------------------------------
#define NE4 (BS * TS * VDIM / 4)      // 2097152
#define NW4 (NHD * VDIM / 4)          // 262144
#define NCVT ((NE4 + 2 * NW4) / 256)  // 10240
#define NQ2  (NHD / 4)                // 512 query blocks (4 waves each)
#define NZERO 80                      // 80*256 float4 = 81920 floats
__global__ void k_pre(const float* __restrict__ enc, const float* __restrict__ Wk,
                      const float* __restrict__ Wv, __bf16* __restrict__ enc_bf,
                      __bf16* __restrict__ wk_bf, __bf16* __restrict__ wv_bf,
                      const float* __restrict__ dec, const float* __restrict__ Wq,
                      const float* __restrict__ bq, float* __restrict__ query,
                      const float* __restrict__ convw, float* __restrict__ P,
                      float* __restrict__ zbase) {
    const int bx = blockIdx.x;
    if (bx < NCVT) {
        int i = bx * blockDim.x + threadIdx.x;
        const float* src; __bf16* dst; int k;
        if (i < NE4)            { src = enc; dst = enc_bf; k = i; }
        else if (i < NE4 + NW4) { src = Wk;  dst = wk_bf;  k = i - NE4; }
        else                    { src = Wv;  dst = wv_bf;  k = i - NE4 - NW4; }
        float4 v = ((const float4*)src)[k];
        bf16x4 o;
        o[0] = (__bf16)v.x; o[1] = (__bf16)v.y; o[2] = (__bf16)v.z; o[3] = (__bf16)v.w;
        ((bf16x4*)dst)[k] = o;
    } else if (bx < NCVT + NQ2) {
        int o = (bx - NCVT) * 4 + (threadIdx.x >> 6);    // 0..2047
        int lane = threadIdx.x & 63;
        const float* wr = Wq + (size_t)o * QDIM;
        float s[BS];
        #pragma unroll
        for (int b = 0; b < BS; ++b) s[b] = 0.f;
        #pragma unroll
        for (int i = 0; i < QDIM / 64; ++i) {
            float wv = wr[lane + 64 * i];
            #pragma unroll
            for (int b = 0; b < BS; ++b)
                s[b] = fmaf(wv, dec[b * QDIM + lane + 64 * i], s[b]);
        }
        #pragma unroll
        for (int off = 32; off > 0; off >>= 1)
            #pragma unroll
            for (int b = 0; b < BS; ++b) s[b] += __shfl_down(s[b], off);
        if (lane == 0) {
            float bias = bq[o];
            #pragma unroll
            for (int b = 0; b < BS; ++b) query[b * NHD + o] = tanhf(s[b] + bias);
        }
    } else if (bx == NCVT + NQ2) {
        // conv prefix: P[j][k] = sum_{dt<j} sum_h convw[k,h,dt]
        __shared__ float cs[KN * (2 * KS + 1)];    // 80.4 KB
        int tid = threadIdx.x;                     // 256
        for (int i = tid; i < KN * (2 * KS + 1); i += 256) {
            int k = i / (2 * KS + 1);
            int dt = i - k * (2 * KS + 1);
            const float* wr = convw + k * (NH * (2 * KS + 1)) + dt;
            cs[i] = wr[0] + wr[201] + wr[402] + wr[603];
        }
        __syncthreads();
        if (tid < KN) {
            float acc = 0.f;
            P[tid] = 0.f;
            const float* c = cs + tid * (2 * KS + 1);
            for (int dt = 0; dt < 2 * KS + 1; ++dt) {
                acc += c[dt];
                P[(dt + 1) * KN + tid] = acc;
            }
        }
    } else {
        int z = (bx - NCVT - NQ2 - 1) * 256 + threadIdx.x;   // float4 idx
        ((float4*)zbase)[z] = make_float4(0.f, 0.f, 0.f, 0.f);
    }
}

// ---------------------------------------------------------------------------
// Qtab[j,d] = sum_k projw[d,k] * P[j,k]
// ---------------------------------------------------------------------------
__global__ void k_qtab(const float* __restrict__ P, const float* __restrict__ projw,
                       float* __restrict__ Qtab) {
    int j = blockIdx.x;       // 0..201
    __shared__ float Pc[KN];
    int tid = threadIdx.x;    // 512
    if (tid < KN) Pc[tid] = P[j * KN + tid];
    __syncthreads();
    const float* pr = projw + tid * KN;
    float s = 0.f;
    #pragma unroll 4
    for (int k = 0; k < KN; ++k) s = fmaf(pr[k], Pc[k], s);
    Qtab[j * DIM + tid] = s;
}

// ===========================================================================
// GEMM core (R8 config — best known): 128x128 tile, BK=32, 512 threads =
// 8 waves 2x4, wave tile 64x32 (acc 32 regs, VGPR 40, no spills).
// Double-buffered LDS (32 KB), one barrier/iter, loop-invariant addresses.
// XCD-pinned flat grid: bid = ((b*16 + t0b)*2 + nhi)*8 + nlo -> XCD = nlo
// holds a 256 KB B slice L2-resident; 16 blocks sharing an A tile run in
// the same window -> A served once from L3.
// ===========================================================================
#define GEMM1(Bptr)                                                               \
    const int bid = blockIdx.x;                                                    \
    const int b   = bid >> 8;                                                      \
    const int t0  = ((bid >> 4) & 15) << 7;                                        \
    const int n0  = ((((bid >> 3) & 1) << 3) | (bid & 7)) << 7;                    \
    const int len = enc_len[b];                                                    \
    if (t0 >= len) return;                                                         \
    const int tid = threadIdx.x;                                                   \
    const int w = tid >> 6, lane = tid & 63;                                       \
    const int wy = w >> 2, wx = w & 3;                                             \
    const int col = lane & 15, quad = lane >> 4;                                   \
    __shared__ __bf16 Ash[2 * 4096];                                               \
    __shared__ __bf16 Bsh[2 * 4096];                                               \
    f32x4 acc[4][2];                                                               \
    _Pragma("unroll")                                                              \
    for (int i = 0; i < 4; ++i)                                                    \
        _Pragma("unroll")                                                          \
        for (int j = 0; j < 2; ++j) acc[i][j] = (f32x4)0.f;                        \
    const __bf16* Abase = enc_bf + ((size_t)b * TS + t0) * VDIM;                   \
    const int sm = tid >> 2;                                                       \
    const int sj = (tid & 3) ^ (sm & 3) ^ ((sm >> 2) & 3);                         \
    const __bf16* gpA = Abase + (size_t)sm * VDIM + sj * 8;                        \
    const __bf16* gpB = (Bptr) + ((size_t)n0 + sm) * VDIM + sj * 8;                \
    const int cfr = quad ^ (col & 3) ^ ((col >> 2) & 3);                           \
    const char* pA = (const char*)Ash + (((wy * 64 + col) * 4 + cfr) << 4);        \
    const char* pB = (const char*)Bsh + (((wx * 32 + col) * 4 + cfr) << 4);        \
    __builtin_amdgcn_global_load_lds(AS1(gpA), AS3(Ash + w * 512), 16, 0, 0);      \
    __builtin_amdgcn_global_load_lds(AS1(gpB), AS3(Bsh + w * 512), 16, 0, 0);      \
    gpA += 32; gpB += 32;                                                          \
    for (int kk = 0; kk < 16; ++kk) {                                              \
        __syncthreads();                                                           \
        if (kk < 15) {                                                             \
            int nb_ = ((kk + 1) & 1) * 4096;                                       \
            __builtin_amdgcn_global_load_lds(AS1(gpA), AS3(Ash + nb_ + w * 512), 16, 0, 0); \
            __builtin_amdgcn_global_load_lds(AS1(gpB), AS3(Bsh + nb_ + w * 512), 16, 0, 0); \
            gpA += 32; gpB += 32;                                                  \
        }                                                                          \
        const int bo = (kk & 1) * 8192;                                            \
        bf16x8 af[4], bfr[2];                                                      \
        _Pragma("unroll")                                                          \
        for (int i = 0; i < 4; ++i) af[i] = *(const bf16x8*)(pA + bo + i * 1024);  \
        _Pragma("unroll")                                                          \
        for (int j = 0; j < 2; ++j) bfr[j] = *(const bf16x8*)(pB + bo + j * 1024); \
        _Pragma("unroll")                                                          \
        for (int i = 0; i < 4; ++i)                                                \
            _Pragma("unroll")                                                      \
            for (int j = 0; j < 2; ++j)                                            \
                acc[i][j] = __builtin_amdgcn_mfma_f32_16x16x32_bf16(               \
                    af[i], bfr[j], acc[i][j], 0, 0, 0);                            \
    }                                                                              \
    __syncthreads();
// acc[i][j][r] = C[t0+wy*64+i*16+quad*4+r][n0+wx*32+j*16+col]

// ---------------------------------------------------------------------------
// Energy pass: C = enc @ Wk^T, epilogue:
//   energy[b,h,t] += sum_n tanh(tanh(C+bk)+query+loc) * gen_w[d]
// ---------------------------------------------------------------------------
__global__ __launch_bounds__(512, 4) void k_energy(
    const __bf16* __restrict__ enc_bf, const __bf16* __restrict__ wk_bf,
    const float* __restrict__ bk, const float* __restrict__ gen_w,
    const int* __restrict__ enc_len, const float* __restrict__ query,
    const float* __restrict__ Qtab, float* __restrict__ energy) {
    GEMM1(wk_bf)

    const int h = n0 >> 9;
    const float inv_len = 1.0f / (float)len;
    float qv[2], gw[2], bkv[2], lI[2];
    int dj[2];
    #pragma unroll
    for (int j = 0; j < 2; ++j) {
        int n = n0 + wx * 32 + j * 16 + col;
        dj[j] = n & (DIM - 1);
        qv[j] = query[b * NHD + n];
        gw[j] = gen_w[dj[j]];
        bkv[j] = bk[n];
        lI[j] = fast_tanh((Qtab[(2 * KS + 1) * DIM + dj[j]] - Qtab[dj[j]]) * inv_len);
    }
    float* red = (float*)Ash;   // [128][4]
    #pragma unroll
    for (int i = 0; i < 4; ++i) {
        #pragma unroll
        for (int r = 0; r < 4; ++r) {
            int tl = wy * 64 + i * 16 + quad * 4 + r;
            int t = t0 + tl;
            float l[2];
            if (t >= KS && t < len - KS) {           // interior: loc const in t
                #pragma unroll
                for (int j = 0; j < 2; ++j) l[j] = lI[j];
            } else {
                int lo = KS - t; if (lo < 0) lo = 0;
                int hi = KS - t + len - 1; if (hi > 2 * KS) hi = 2 * KS;
                bool has = (hi >= lo);
                #pragma unroll
                for (int j = 0; j < 2; ++j) {
                    float cv = has
                        ? (Qtab[(hi + 1) * DIM + dj[j]] - Qtab[lo * DIM + dj[j]]) * inv_len
                        : 0.f;
                    l[j] = fast_tanh(cv);
                }
            }
            float s = 0.f;
            #pragma unroll
            for (int j = 0; j < 2; ++j) {
                float key = fast_tanh(acc[i][j][r] + bkv[j]);
                float e = fast_tanh(key + qv[j] + l[j]);
                s = fmaf(e, gw[j], s);
            }
            s += __shfl_xor(s, 1); s += __shfl_xor(s, 2);
            s += __shfl_xor(s, 4); s += __shfl_xor(s, 8);
            if (col == 0) red[tl * 4 + wx] = s;
        }
    }
    __syncthreads();
    if (tid < 128) {
        float s = red[tid * 4] + red[tid * 4 + 1] + red[tid * 4 + 2] + red[tid * 4 + 3];
        atomicAdd(&energy[(size_t)(b * NH + h) * TS + t0 + tid], s);
    }
}

// ---------------------------------------------------------------------------
// ctx pass: C = enc @ Wv^T, epilogue: ctx[b,n] += sum_t attn * tanh(C + bv)
// ---------------------------------------------------------------------------
__global__ __launch_bounds__(512, 4) void k_ctxg(
    const __bf16* __restrict__ enc_bf, const __bf16* __restrict__ wv_bf,
    const float* __restrict__ bv, const float* __restrict__ attn,
    const int* __restrict__ enc_len, float* __restrict__ ctx) {
    GEMM1(wv_bf)

    const int h = n0 >> 9;
    float att[4][4];
    #pragma unroll
    for (int i = 0; i < 4; ++i)
        #pragma unroll
        for (int r = 0; r < 4; ++r)
            att[i][r] = attn[(size_t)(b * NH + h) * TS + t0 + wy * 64 + i * 16 + quad * 4 + r];
    float* red = (float*)Ash;   // [128][2]
    #pragma unroll
    for (int j = 0; j < 2; ++j) {
        int nl = wx * 32 + j * 16 + col;
        float bvn = bv[n0 + nl];
        float s = 0.f;
        #pragma unroll
        for (int i = 0; i < 4; ++i)
            #pragma unroll
            for (int r = 0; r < 4; ++r)
                s = fmaf(att[i][r], fast_tanh(acc[i][j][r] + bvn), s);
        s += __shfl_xor(s, 16); s += __shfl_xor(s, 32);
        if (quad == 0) red[nl * 2 + wy] = s;
    }
    __syncthreads();
    if (tid < 128) {
        float s = red[tid * 2] + red[tid * 2 + 1];
        atomicAdd(&ctx[(size_t)b * NHD + n0 + tid], s);
    }
}

// ---------------------------------------------------------------------------
// softmax over t (masked), shuffle-based, writes attn to d_out
// ---------------------------------------------------------------------------
__global__ void k_softmax(const float* __restrict__ energy, const int* __restrict__ enc_len,
                          const float* __restrict__ gen_b, float* __restrict__ attn) {
    int bh = blockIdx.x;          // 32
    int b = bh >> 2;
    int len = enc_len[b];
    int tid = threadIdx.x;        // 512
    int w = tid >> 6, lane = tid & 63;
    const float gb = gen_b[0];
    float ev[4];
    float mx = -INFINITY;
    #pragma unroll
    for (int i = 0; i < 4; ++i) {
        int t = i * 512 + tid;
        float e = (t < len) ? (energy[(size_t)bh * TS + t] + gb) * (1.0f / TEMPERATURE)
                            : -INFINITY;
        ev[i] = e;
        mx = fmaxf(mx, e);
    }
    __shared__ float sred[8], ssum[8];
    #pragma unroll
    for (int off = 32; off > 0; off >>= 1) mx = fmaxf(mx, __shfl_xor(mx, off));
    if (lane == 0) sred[w] = mx;
    __syncthreads();
    #pragma unroll
    for (int k = 0; k < 8; ++k) mx = fmaxf(mx, sred[k]);
    float ls = 0.f;
    #pragma unroll
    for (int i = 0; i < 4; ++i) {
        float ex = __expf(ev[i] - mx);
        ev[i] = ex;
        ls += ex;
    }
    #pragma unroll
    for (int off = 32; off > 0; off >>= 1) ls += __shfl_xor(ls, off);
    if (lane == 0) ssum[w] = ls;
    __syncthreads();
    float tot = 0.f;
    #pragma unroll
    for (int k = 0; k < 8; ++k) tot += ssum[k];
    float inv = 1.0f / tot;
    #pragma unroll
    for (int i = 0; i < 4; ++i)
        attn[(size_t)bh * TS + i * 512 + tid] = ev[i] * inv;
}

// ---------------------------------------------------------------------------
// context[b,o] = ctx[b,:] . merge_w[o,:] + merge_b[o]
// one WAVE per output o, loops all 8 batches -> merge_w read once (4 MB)
// ---------------------------------------------------------------------------
__global__ void k_merge(const float* __restrict__ ctx, const float* __restrict__ mw,
                        const float* __restrict__ mb, float* __restrict__ out) {
    int o = blockIdx.x * 4 + (threadIdx.x >> 6);   // 0..511
    int lane = threadIdx.x & 63;
    const float* wr = mw + (size_t)o * NHD;
    float s[BS];
    #pragma unroll
    for (int b = 0; b < BS; ++b) s[b] = 0.f;
    #pragma unroll
    for (int i = 0; i < NHD / 64; ++i) {
        float wv = wr[lane + 64 * i];
        #pragma unroll
        for (int b = 0; b < BS; ++b)
            s[b] = fmaf(wv, ctx[b * NHD + lane + 64 * i], s[b]);
    }
    #pragma unroll
    for (int off = 32; off > 0; off >>= 1)
        #pragma unroll
        for (int b = 0; b < BS; ++b) s[b] += __shfl_down(s[b], off);
    if (lane == 0) {
        float bias = mb[o];
        #pragma unroll
        for (int b = 0; b < BS; ++b) out[b * VDIM + o] = s[b] + bias;
    }
}

extern "C" void kernel_launch(void* const* d_in, const int* in_sizes, int n_in,
                              void* d_out, int out_size, void* d_ws, size_t ws_size,
                              hipStream_t stream) {
    const float* dec     = (const float*)d_in[0];
    const float* enc     = (const float*)d_in[1];
    const int*   enc_len = (const int*)d_in[2];
    const float* Wq      = (const float*)d_in[3];
    const float* bq      = (const float*)d_in[4];
    const float* Wk      = (const float*)d_in[5];
    const float* bk      = (const float*)d_in[6];
    const float* Wv      = (const float*)d_in[7];
    const float* bv      = (const float*)d_in[8];
    const float* convw   = (const float*)d_in[9];
    const float* projw   = (const float*)d_in[10];
    const float* gen_w   = (const float*)d_in[11];
    const float* gen_b   = (const float*)d_in[12];
    const float* merge_w = (const float*)d_in[13];
    const float* merge_b = (const float*)d_in[14];

    float* out   = (float*)d_out;               // attn [65536] ++ context [4096]
    float* ws    = (float*)d_ws;
    float* query = ws + WS_QUERY;
    float* Qtab  = ws + WS_QTAB;
    float* energy= ws + WS_ENERGY;
    float* ctx   = ws + WS_CTX;
    float* Pws   = ws + WS_P;
    __bf16* enc_bf = (__bf16*)((char*)d_ws + (size_t)WS_F32_END * 4);
    __bf16* wk_bf  = enc_bf + (size_t)BS * TS * VDIM;
    __bf16* wv_bf  = wk_bf + (size_t)NHD * VDIM;

    k_pre<<<dim3(NCVT + NQ2 + 1 + NZERO), dim3(256), 0, stream>>>(
        enc, Wk, Wv, enc_bf, wk_bf, wv_bf, dec, Wq, bq, query, convw, Pws,
        energy /* zbase: energy+ctx contiguous 81920 floats */);
    k_qtab<<<dim3(2 * KS + 2), dim3(512), 0, stream>>>(Pws, projw, Qtab);
    k_energy<<<dim3(2048), dim3(512), 0, stream>>>(
        enc_bf, wk_bf, bk, gen_w, enc_len, query, Qtab, energy);
    k_softmax<<<dim3(BS * NH), dim3(512), 0, stream>>>(energy, enc_len, gen_b, out);
    k_ctxg<<<dim3(2048), dim3(512), 0, stream>>>(
        enc_bf, wv_bf, bv, out, enc_len, ctx);
    k_merge<<<dim3(VDIM / 4), dim3(256), 0, stream>>>(ctx, merge_w, merge_b, out + 65536);
}

// Round 12
// 309.319 us; speedup vs baseline: 1.1368x; 1.0049x over previous
//
#include <hip/hip_runtime.h>
#include <math.h>

#define NH 4
#define DIM 512
#define VDIM 512
#define QDIM 1024
#define KS 100
#define KN 100
#define TEMPERATURE 0.5f
#define BS 8
#define TS 2048
#define NHD (NH * DIM)          // 2048

// workspace layout (floats)
#define WS_QUERY   0                      // 16384
#define WS_QTAB    16384                  // 202*512 = 103424
#define WS_ENERGYP 119808                 // 4*32*2048 = 262144 (partial planes)
#define WS_CTX     381952                 // 16384
#define WS_P       398336                 // 202*100 = 20200
#define WS_F32_END 418536                 // *4 bytes (16B aligned)
// bf16 region: enc_bf [8388608 el], wk_bf [1048576], wv_bf [1048576]

typedef __bf16 bf16x8 __attribute__((ext_vector_type(8)));
typedef __bf16 bf16x4 __attribute__((ext_vector_type(4)));
typedef float  f32x4  __attribute__((ext_vector_type(4)));

#define AS1(p) ((const __attribute__((address_space(1))) void*)(p))
#define AS3(p) ((__attribute__((address_space(3))) void*)(p))

// tanh(x) = 1 - 2/(e^{2x}+1). Clamp-free: exp->inf => rcp->0 => 1;
// exp->0 => 1-2 = -1. 5 VALU inst (mul, exp, add, rcp, fma) vs 8 before.
__device__ __forceinline__ float fast_tanh(float x) {
    float e = __expf(2.0f * x);
    return 1.0f - __fdividef(2.0f, e + 1.0f);
}

// ---------------------------------------------------------------------------
// k_pre: one dispatch, 3 independent jobs:
//   [0, NCVT)      fp32->bf16 cvt of enc/Wk/Wv
//   [NCVT, +NQ2)   query GEMV: one WAVE per output o, loops all 8 batches
//   [NCVT+NQ2]     conv prefix (LDS-staged)
// ---------------------------------------------------------------------------
#define NE4 (BS * TS * VDIM / 4)      // 2097152
#define NW4 (NHD * VDIM / 4)          // 262144
#define NCVT ((NE4 + 2 * NW4) / 256)  // 10240
#define NQ2  (NHD / 4)                // 512 query blocks (4 waves each)
__global__ void k_pre(const float* __restrict__ enc, const float* __restrict__ Wk,
                      const float* __restrict__ Wv, __bf16* __restrict__ enc_bf,
                      __bf16* __restrict__ wk_bf, __bf16* __restrict__ wv_bf,
                      const float* __restrict__ dec, const float* __restrict__ Wq,
                      const float* __restrict__ bq, float* __restrict__ query,
                      const float* __restrict__ convw, float* __restrict__ P) {
    const int bx = blockIdx.x;
    if (bx < NCVT) {
        int i = bx * blockDim.x + threadIdx.x;
        const float* src; __bf16* dst; int k;
        if (i < NE4)            { src = enc; dst = enc_bf; k = i; }
        else if (i < NE4 + NW4) { src = Wk;  dst = wk_bf;  k = i - NE4; }
        else                    { src = Wv;  dst = wv_bf;  k = i - NE4 - NW4; }
        float4 v = ((const float4*)src)[k];
        bf16x4 o;
        o[0] = (__bf16)v.x; o[1] = (__bf16)v.y; o[2] = (__bf16)v.z; o[3] = (__bf16)v.w;
        ((bf16x4*)dst)[k] = o;
    } else if (bx < NCVT + NQ2) {
        int o = (bx - NCVT) * 4 + (threadIdx.x >> 6);    // 0..2047
        int lane = threadIdx.x & 63;
        const float* wr = Wq + (size_t)o * QDIM;
        float s[BS];
        #pragma unroll
        for (int b = 0; b < BS; ++b) s[b] = 0.f;
        #pragma unroll
        for (int i = 0; i < QDIM / 64; ++i) {
            float wv = wr[lane + 64 * i];
            #pragma unroll
            for (int b = 0; b < BS; ++b)
                s[b] = fmaf(wv, dec[b * QDIM + lane + 64 * i], s[b]);
        }
        #pragma unroll
        for (int off = 32; off > 0; off >>= 1)
            #pragma unroll
            for (int b = 0; b < BS; ++b) s[b] += __shfl_down(s[b], off);
        if (lane == 0) {
            float bias = bq[o];
            #pragma unroll
            for (int b = 0; b < BS; ++b) query[b * NHD + o] = tanhf(s[b] + bias);
        }
    } else {
        // conv prefix: P[j][k] = sum_{dt<j} sum_h convw[k,h,dt]
        __shared__ float cs[KN * (2 * KS + 1)];    // 80.4 KB
        int tid = threadIdx.x;                     // 256
        for (int i = tid; i < KN * (2 * KS + 1); i += 256) {
            int k = i / (2 * KS + 1);
            int dt = i - k * (2 * KS + 1);
            const float* wr = convw + k * (NH * (2 * KS + 1)) + dt;
            cs[i] = wr[0] + wr[201] + wr[402] + wr[603];
        }
        __syncthreads();
        if (tid < KN) {
            float acc = 0.f;
            P[tid] = 0.f;
            const float* c = cs + tid * (2 * KS + 1);
            for (int dt = 0; dt < 2 * KS + 1; ++dt) {
                acc += c[dt];
                P[(dt + 1) * KN + tid] = acc;
            }
        }
    }
}

// ---------------------------------------------------------------------------
// Qtab[j,d] = sum_k projw[d,k] * P[j,k]; spare blocks zero the ctx accumulator
// ---------------------------------------------------------------------------
__global__ void k_qtab(const float* __restrict__ P, const float* __restrict__ projw,
                       float* __restrict__ Qtab, float* __restrict__ ctx) {
    int tid = threadIdx.x;    // 512
    if (blockIdx.x >= 2 * KS + 2) {
        int z = (blockIdx.x - (2 * KS + 2)) * 512 + tid;   // float4 idx, 4096 total
        ((float4*)ctx)[z] = make_float4(0.f, 0.f, 0.f, 0.f);
        return;
    }
    int j = blockIdx.x;       // 0..201
    __shared__ float Pc[KN];
    if (tid < KN) Pc[tid] = P[j * KN + tid];
    __syncthreads();
    const float* pr = projw + tid * KN;
    float s = 0.f;
    #pragma unroll 4
    for (int k = 0; k < KN; ++k) s = fmaf(pr[k], Pc[k], s);
    Qtab[j * DIM + tid] = s;
}

// ===========================================================================
// GEMM core (R8 config — best known): 128x128 tile, BK=32, 512 threads =
// 8 waves 2x4, wave tile 64x32 (acc 32 regs, VGPR 40, no spills).
// Double-buffered LDS (32 KB), one barrier/iter, loop-invariant addresses.
// XCD-pinned flat grid: bid = ((b*16 + t0b)*2 + nhi)*8 + nlo -> XCD = nlo
// holds a 256 KB B slice L2-resident; 16 blocks sharing an A tile run in
// the same window -> A served once from L3.
// ===========================================================================
#define GEMM1(Bptr)                                                               \
    const int bid = blockIdx.x;                                                    \
    const int b   = bid >> 8;                                                      \
    const int t0  = ((bid >> 4) & 15) << 7;                                        \
    const int n0  = ((((bid >> 3) & 1) << 3) | (bid & 7)) << 7;                    \
    const int len = enc_len[b];                                                    \
    if (t0 >= len) return;                                                         \
    const int tid = threadIdx.x;                                                   \
    const int w = tid >> 6, lane = tid & 63;                                       \
    const int wy = w >> 2, wx = w & 3;                                             \
    const int col = lane & 15, quad = lane >> 4;                                   \
    __shared__ __bf16 Ash[2 * 4096];                                               \
    __shared__ __bf16 Bsh[2 * 4096];                                               \
    f32x4 acc[4][2];                                                               \
    _Pragma("unroll")                                                              \
    for (int i = 0; i < 4; ++i)                                                    \
        _Pragma("unroll")                                                          \
        for (int j = 0; j < 2; ++j) acc[i][j] = (f32x4)0.f;                        \
    const __bf16* Abase = enc_bf + ((size_t)b * TS + t0) * VDIM;                   \
    const int sm = tid >> 2;                                                       \
    const int sj = (tid & 3) ^ (sm & 3) ^ ((sm >> 2) & 3);                         \
    const __bf16* gpA = Abase + (size_t)sm * VDIM + sj * 8;                        \
    const __bf16* gpB = (Bptr) + ((size_t)n0 + sm) * VDIM + sj * 8;                \
    const int cfr = quad ^ (col & 3) ^ ((col >> 2) & 3);                           \
    const char* pA = (const char*)Ash + (((wy * 64 + col) * 4 + cfr) << 4);        \
    const char* pB = (const char*)Bsh + (((wx * 32 + col) * 4 + cfr) << 4);        \
    __builtin_amdgcn_global_load_lds(AS1(gpA), AS3(Ash + w * 512), 16, 0, 0);      \
    __builtin_amdgcn_global_load_lds(AS1(gpB), AS3(Bsh + w * 512), 16, 0, 0);      \
    gpA += 32; gpB += 32;                                                          \
    for (int kk = 0; kk < 16; ++kk) {                                              \
        __syncthreads();                                                           \
        if (kk < 15) {                                                             \
            int nb_ = ((kk + 1) & 1) * 4096;                                       \
            __builtin_amdgcn_global_load_lds(AS1(gpA), AS3(Ash + nb_ + w * 512), 16, 0, 0); \
            __builtin_amdgcn_global_load_lds(AS1(gpB), AS3(Bsh + nb_ + w * 512), 16, 0, 0); \
            gpA += 32; gpB += 32;                                                  \
        }                                                                          \
        const int bo = (kk & 1) * 8192;                                            \
        bf16x8 af[4], bfr[2];                                                      \
        _Pragma("unroll")                                                          \
        for (int i = 0; i < 4; ++i) af[i] = *(const bf16x8*)(pA + bo + i * 1024);  \
        _Pragma("unroll")                                                          \
        for (int j = 0; j < 2; ++j) bfr[j] = *(const bf16x8*)(pB + bo + j * 1024); \
        _Pragma("unroll")                                                          \
        for (int i = 0; i < 4; ++i)                                                \
            _Pragma("unroll")                                                      \
            for (int j = 0; j < 2; ++j)                                            \
                acc[i][j] = __builtin_amdgcn_mfma_f32_16x16x32_bf16(               \
                    af[i], bfr[j], acc[i][j], 0, 0, 0);                            \
    }                                                                              \
    __syncthreads();
// acc[i][j][r] = C[t0+wy*64+i*16+quad*4+r][n0+wx*32+j*16+col]

// ---------------------------------------------------------------------------
// Energy pass: C = enc @ Wk^T, epilogue writes PARTIAL plane p = (n0>>7)&3:
//   energyP[p][b,h,t] = sum_{n in tile} tanh(tanh(C+bk)+query+loc) * gen_w[d]
// ---------------------------------------------------------------------------
__global__ __launch_bounds__(512, 4) void k_energy(
    const __bf16* __restrict__ enc_bf, const __bf16* __restrict__ wk_bf,
    const float* __restrict__ bk, const float* __restrict__ gen_w,
    const int* __restrict__ enc_len, const float* __restrict__ query,
    const float* __restrict__ Qtab, float* __restrict__ energyP) {
    GEMM1(wk_bf)

    const int h = n0 >> 9;
    const float inv_len = 1.0f / (float)len;
    float qv[2], gw[2], bkv[2], lI[2];
    int dj[2];
    #pragma unroll
    for (int j = 0; j < 2; ++j) {
        int n = n0 + wx * 32 + j * 16 + col;
        dj[j] = n & (DIM - 1);
        qv[j] = query[b * NHD + n];
        gw[j] = gen_w[dj[j]];
        bkv[j] = bk[n];
        lI[j] = fast_tanh((Qtab[(2 * KS + 1) * DIM + dj[j]] - Qtab[dj[j]]) * inv_len);
    }
    float* red = (float*)Ash;   // [128][4]
    #pragma unroll
    for (int i = 0; i < 4; ++i) {
        #pragma unroll
        for (int r = 0; r < 4; ++r) {
            int tl = wy * 64 + i * 16 + quad * 4 + r;
            int t = t0 + tl;
            float l[2];
            if (t >= KS && t < len - KS) {           // interior: loc const in t
                #pragma unroll
                for (int j = 0; j < 2; ++j) l[j] = lI[j];
            } else {
                int lo = KS - t; if (lo < 0) lo = 0;
                int hi = KS - t + len - 1; if (hi > 2 * KS) hi = 2 * KS;
                bool has = (hi >= lo);
                #pragma unroll
                for (int j = 0; j < 2; ++j) {
                    float cv = has
                        ? (Qtab[(hi + 1) * DIM + dj[j]] - Qtab[lo * DIM + dj[j]]) * inv_len
                        : 0.f;
                    l[j] = fast_tanh(cv);
                }
            }
            float s = 0.f;
            #pragma unroll
            for (int j = 0; j < 2; ++j) {
                float key = fast_tanh(acc[i][j][r] + bkv[j]);
                float e = fast_tanh(key + qv[j] + l[j]);
                s = fmaf(e, gw[j], s);
            }
            s += __shfl_xor(s, 1); s += __shfl_xor(s, 2);
            s += __shfl_xor(s, 4); s += __shfl_xor(s, 8);
            if (col == 0) red[tl * 4 + wx] = s;
        }
    }
    __syncthreads();
    if (tid < 128) {
        float s = red[tid * 4] + red[tid * 4 + 1] + red[tid * 4 + 2] + red[tid * 4 + 3];
        energyP[(size_t)((n0 >> 7) & 3) * 65536 + (size_t)(b * NH + h) * TS + t0 + tid] = s;
    }
}

// ---------------------------------------------------------------------------
// ctx pass: C = enc @ Wv^T, epilogue: ctx[b,n] += sum_t attn * tanh(C + bv)
// ---------------------------------------------------------------------------
__global__ __launch_bounds__(512, 4) void k_ctxg(
    const __bf16* __restrict__ enc_bf, const __bf16* __restrict__ wv_bf,
    const float* __restrict__ bv, const float* __restrict__ attn,
    const int* __restrict__ enc_len, float* __restrict__ ctx) {
    GEMM1(wv_bf)

    const int h = n0 >> 9;
    float att[4][4];
    #pragma unroll
    for (int i = 0; i < 4; ++i)
        #pragma unroll
        for (int r = 0; r < 4; ++r)
            att[i][r] = attn[(size_t)(b * NH + h) * TS + t0 + wy * 64 + i * 16 + quad * 4 + r];
    float* red = (float*)Ash;   // [128][2]
    #pragma unroll
    for (int j = 0; j < 2; ++j) {
        int nl = wx * 32 + j * 16 + col;
        float bvn = bv[n0 + nl];
        float s = 0.f;
        #pragma unroll
        for (int i = 0; i < 4; ++i)
            #pragma unroll
            for (int r = 0; r < 4; ++r)
                s = fmaf(att[i][r], fast_tanh(acc[i][j][r] + bvn), s);
        s += __shfl_xor(s, 16); s += __shfl_xor(s, 32);
        if (quad == 0) red[nl * 2 + wy] = s;
    }
    __syncthreads();
    if (tid < 128) {
        float s = red[tid * 2] + red[tid * 2 + 1];
        atomicAdd(&ctx[(size_t)b * NHD + n0 + tid], s);
    }
}

// ---------------------------------------------------------------------------
// softmax over t (masked): sums the 4 energy partial planes, writes attn
// ---------------------------------------------------------------------------
__global__ void k_softmax(const float* __restrict__ energyP, const int* __restrict__ enc_len,
                          const float* __restrict__ gen_b, float* __restrict__ attn) {
    int bh = blockIdx.x;          // 32
    int b = bh >> 2;
    int len = enc_len[b];
    int tid = threadIdx.x;        // 512
    int w = tid >> 6, lane = tid & 63;
    const float gb = gen_b[0];
    const float* e0 = energyP + (size_t)bh * TS;
    float ev[4];
    float mx = -INFINITY;
    #pragma unroll
    for (int i = 0; i < 4; ++i) {
        int t = i * 512 + tid;
        float e = -INFINITY;
        if (t < len) {
            float s = e0[t] + e0[65536 + t] + e0[131072 + t] + e0[196608 + t];
            e = (s + gb) * (1.0f / TEMPERATURE);
        }
        ev[i] = e;
        mx = fmaxf(mx, e);
    }
    __shared__ float sred[8], ssum[8];
    #pragma unroll
    for (int off = 32; off > 0; off >>= 1) mx = fmaxf(mx, __shfl_xor(mx, off));
    if (lane == 0) sred[w] = mx;
    __syncthreads();
    #pragma unroll
    for (int k = 0; k < 8; ++k) mx = fmaxf(mx, sred[k]);
    float ls = 0.f;
    #pragma unroll
    for (int i = 0; i < 4; ++i) {
        float ex = __expf(ev[i] - mx);
        ev[i] = ex;
        ls += ex;
    }
    #pragma unroll
    for (int off = 32; off > 0; off >>= 1) ls += __shfl_xor(ls, off);
    if (lane == 0) ssum[w] = ls;
    __syncthreads();
    float tot = 0.f;
    #pragma unroll
    for (int k = 0; k < 8; ++k) tot += ssum[k];
    float inv = 1.0f / tot;
    #pragma unroll
    for (int i = 0; i < 4; ++i)
        attn[(size_t)bh * TS + i * 512 + tid] = ev[i] * inv;
}

// ---------------------------------------------------------------------------
// context[b,o] = ctx[b,:] . merge_w[o,:] + merge_b[o]
// one WAVE per output o, loops all 8 batches -> merge_w read once (4 MB)
// ---------------------------------------------------------------------------
__global__ void k_merge(const float* __restrict__ ctx, const float* __restrict__ mw,
                        const float* __restrict__ mb, float* __restrict__ out) {
    int o = blockIdx.x * 4 + (threadIdx.x >> 6);   // 0..511
    int lane = threadIdx.x & 63;
    const float* wr = mw + (size_t)o * NHD;
    float s[BS];
    #pragma unroll
    for (int b = 0; b < BS; ++b) s[b] = 0.f;
    #pragma unroll
    for (int i = 0; i < NHD / 64; ++i) {
        float wv = wr[lane + 64 * i];
        #pragma unroll
        for (int b = 0; b < BS; ++b)
            s[b] = fmaf(wv, ctx[b * NHD + lane + 64 * i], s[b]);
    }
    #pragma unroll
    for (int off = 32; off > 0; off >>= 1)
        #pragma unroll
        for (int b = 0; b < BS; ++b) s[b] += __shfl_down(s[b], off);
    if (lane == 0) {
        float bias = mb[o];
        #pragma unroll
        for (int b = 0; b < BS; ++b) out[b * VDIM + o] = s[b] + bias;
    }
}

extern "C" void kernel_launch(void* const* d_in, const int* in_sizes, int n_in,
                              void* d_out, int out_size, void* d_ws, size_t ws_size,
                              hipStream_t stream) {
    const float* dec     = (const float*)d_in[0];
    const float* enc     = (const float*)d_in[1];
    const int*   enc_len = (const int*)d_in[2];
    const float* Wq      = (const float*)d_in[3];
    const float* bq      = (const float*)d_in[4];
    const float* Wk      = (const float*)d_in[5];
    const float* bk      = (const float*)d_in[6];
    const float* Wv      = (const float*)d_in[7];
    const float* bv      = (const float*)d_in[8];
    const float* convw   = (const float*)d_in[9];
    const float* projw   = (const float*)d_in[10];
    const float* gen_w   = (const float*)d_in[11];
    const float* gen_b   = (const float*)d_in[12];
    const float* merge_w = (const float*)d_in[13];
    const float* merge_b = (const float*)d_in[14];

    float* out    = (float*)d_out;               // attn [65536] ++ context [4096]
    float* ws     = (float*)d_ws;
    float* query  = ws + WS_QUERY;
    float* Qtab   = ws + WS_QTAB;
    float* energyP= ws + WS_ENERGYP;
    float* ctx    = ws + WS_CTX;
    float* Pws    = ws + WS_P;
    __bf16* enc_bf = (__bf16*)((char*)d_ws + (size_t)WS_F32_END * 4);
    __bf16* wk_bf  = enc_bf + (size_t)BS * TS * VDIM;
    __bf16* wv_bf  = wk_bf + (size_t)NHD * VDIM;

    k_pre<<<dim3(NCVT + NQ2 + 1), dim3(256), 0, stream>>>(
        enc, Wk, Wv, enc_bf, wk_bf, wv_bf, dec, Wq, bq, query, convw, Pws);
    k_qtab<<<dim3(2 * KS + 2 + 8), dim3(512), 0, stream>>>(Pws, projw, Qtab, ctx);
    k_energy<<<dim3(2048), dim3(512), 0, stream>>>(
        enc_bf, wk_bf, bk, gen_w, enc_len, query, Qtab, energyP);
    k_softmax<<<dim3(BS * NH), dim3(512), 0, stream>>>(energyP, enc_len, gen_b, out);
    k_ctxg<<<dim3(2048), dim3(512), 0, stream>>>(
        enc_bf, wv_bf, bv, out, enc_len, ctx);
    k_merge<<<dim3(VDIM / 4), dim3(256), 0, stream>>>(ctx, merge_w, merge_b, out + 65536);
}